// Round 1
// baseline (129.572 us; speedup 1.0000x reference)
//
#include <hip/hip_runtime.h>
#include <math.h>

#define HH 128
#define WW 128
#define NG 2048
#define DIMV 768
#define PIX (HH * WW)
#define A_MIN (1.0f / 255.0f)
#define TW 16
#define TH 4

// ---------------------------------------------------------------------------
// K1: per-gaussian activation + conic + conservative cull radius.
// Packing (ws):
//   q0[n] = (A/2, B, C/2, opacity)
//   q1[n] = (gx, gy, f0, f1)
//   q2[n] = (f2, r2)   r2 = conservative cull radius^2 in px^2 (or <0 => never visible)
// ---------------------------------------------------------------------------
__global__ __launch_bounds__(256) void prep_kernel(
    const float* __restrict__ xyz, const float* __restrict__ scaling,
    const float* __restrict__ rotation, const float* __restrict__ features,
    const float* __restrict__ opacity,
    float4* __restrict__ q0, float4* __restrict__ q1, float2* __restrict__ q2)
{
    int n = blockIdx.x * 256 + threadIdx.x;
    if (n >= NG) return;
    float mx = tanhf(xyz[2 * n + 0]);
    float my = tanhf(xyz[2 * n + 1]);
    float gx = 0.5f * (mx + 1.0f) * (float)WW;
    float gy = 0.5f * (my + 1.0f) * (float)HH;
    float s0 = fabsf(scaling[2 * n + 0] + 0.5f);
    float s1 = fabsf(scaling[2 * n + 1] + 0.5f);
    float th = 6.28318530717958647692f / (1.0f + expf(-rotation[n]));
    float sn, cs;
    sincosf(th, &sn, &cs);
    float a = cs * s0, b = -sn * s1, d = sn * s0, e = cs * s1;
    float cxx = a * a + b * b;
    float cxy = a * d + b * e;
    float cyy = d * d + e * e;
    float det = cxx * cyy - cxy * cxy;
    float inv = 1.0f / det;
    float A = cyy * inv, B = -cxy * inv, C = cxx * inv;
    float op = opacity[n];
    // alpha >= 1/255 requires sigma <= ln(255*op); sigma >= |d|^2/(2*lmax(cov)),
    // lmax(cov) <= cxx+cyy (strict since det>0) => conservative radius.
    float L = logf(255.0f * op);
    float r2 = (L > 0.0f) ? (2.0f * L * (cxx + cyy)) * 1.0002f + 1e-3f : -1.0f;
    q0[n] = make_float4(0.5f * A, B, 0.5f * C, op);
    q1[n] = make_float4(gx, gy, features[3 * n + 0], features[3 * n + 1]);
    q2[n] = make_float2(features[3 * n + 2], r2);
}

// ---------------------------------------------------------------------------
// K2: one 16x4 pixel tile per block (8 x 32 = 256 tiles), 256 threads (4 waves).
// Phase 0: cull 2048 gaussians vs tile rect (LDS-atomic compaction).
// Phase 1: 4-way wave split over survivors; gaussian index is wave-uniform
//          (readfirstlane) so q0/q1/q2 come in as scalar loads. 1 px/lane.
// Phase 2: LDS reduce + clip, then project to 768 channels with float4 stores.
// ---------------------------------------------------------------------------
__global__ __launch_bounds__(256) void raster_kernel(
    const float4* __restrict__ q0, const float4* __restrict__ q1,
    const float2* __restrict__ q2, const float* __restrict__ w_up,
    const float* __restrict__ b_up, float* __restrict__ out)
{
    __shared__ int s_cnt;
    __shared__ int s_list[NG];
    __shared__ float s_red[4 * 64 * 3];
    __shared__ float s_img[64 * 3];
    __shared__ float4 s_wub[DIMV];

    int tid = threadIdx.x;
    int bx = blockIdx.x & 7, by = blockIdx.x >> 3;
    int px0 = bx * TW, py0 = by * TH;

    if (tid == 0) s_cnt = 0;
    __syncthreads();

    // ---- Phase 0: cull (dist from gaussian center to rect of pixel centers)
    {
        float x0 = px0 + 0.5f, x1 = px0 + TW - 0.5f;
        float y0 = py0 + 0.5f, y1 = py0 + TH - 0.5f;
        for (int g = tid; g < NG; g += 256) {
            float4 c1 = q1[g];
            float2 c2 = q2[g];
            float ddx = fmaxf(fmaxf(x0 - c1.x, c1.x - x1), 0.0f);
            float ddy = fmaxf(fmaxf(y0 - c1.y, c1.y - y1), 0.0f);
            if (ddx * ddx + ddy * ddy <= c2.y) {
                int pos = atomicAdd(&s_cnt, 1);
                s_list[pos] = g;
            }
        }
    }
    // ---- stage w_up/b_up into LDS (overlaps with cull of other waves)
    for (int dd = tid; dd < DIMV; dd += 256) {
        s_wub[dd] = make_float4(w_up[3 * dd + 0], w_up[3 * dd + 1],
                                w_up[3 * dd + 2], b_up[dd]);
    }
    __syncthreads();
    int cnt = s_cnt;

    int lane = tid & 63, wv = tid >> 6;
    // tile pixel index == lane (row-major, 16 wide x 4 tall)
    float pxf = px0 + (lane & 15) + 0.5f;
    float pyf = py0 + (lane >> 4) + 0.5f;

    // ---- Phase 1: alpha-weighted color accumulation
    float ar = 0.0f, ag = 0.0f, ab = 0.0f;
    for (int k = wv; k < cnt; k += 4) {
        int g = __builtin_amdgcn_readfirstlane(s_list[k]);
        float4 a0 = q0[g];
        float4 a1 = q1[g];
        float2 a2 = q2[g];
        float dx = a1.x - pxf, dy = a1.y - pyf;
        float sig = fmaf(a0.y * dx, dy, fmaf(a0.x * dx, dx, a0.z * dy * dy));
        float al = fminf(0.999f, a0.w * __expf(-sig));
        al = (sig < 0.0f || al < A_MIN) ? 0.0f : al;
        ar = fmaf(al, a1.z, ar);
        ag = fmaf(al, a1.w, ag);
        ab = fmaf(al, a2.x, ab);
    }
    s_red[(wv * 64 + lane) * 3 + 0] = ar;
    s_red[(wv * 64 + lane) * 3 + 1] = ag;
    s_red[(wv * 64 + lane) * 3 + 2] = ab;
    __syncthreads();

    if (tid < 64) {
        float sr = 0.0f, sg = 0.0f, sb = 0.0f;
        for (int w = 0; w < 4; ++w) {
            sr += s_red[(w * 64 + tid) * 3 + 0];
            sg += s_red[(w * 64 + tid) * 3 + 1];
            sb += s_red[(w * 64 + tid) * 3 + 2];
        }
        s_img[tid * 3 + 0] = fminf(1.0f, fmaxf(0.0f, sr));
        s_img[tid * 3 + 1] = fminf(1.0f, fmaxf(0.0f, sg));
        s_img[tid * 3 + 2] = fminf(1.0f, fmaxf(0.0f, sb));
    }
    __syncthreads();

    // ---- Phase 2: project to 768 channels, float4 stores (fully coalesced)
    // lane = sub(2b) | row(2b) | colquad(2b): 4 d's x 4 rows x 4 quads per wave instr
    int sub = lane >> 4;
    int r4 = (lane >> 2) & 3;
    int cq = lane & 3;
    int pi = r4 * TW + cq * 4;
    float i00 = s_img[(pi + 0) * 3 + 0], i01 = s_img[(pi + 0) * 3 + 1], i02 = s_img[(pi + 0) * 3 + 2];
    float i10 = s_img[(pi + 1) * 3 + 0], i11 = s_img[(pi + 1) * 3 + 1], i12 = s_img[(pi + 1) * 3 + 2];
    float i20 = s_img[(pi + 2) * 3 + 0], i21 = s_img[(pi + 2) * 3 + 1], i22 = s_img[(pi + 2) * 3 + 2];
    float i30 = s_img[(pi + 3) * 3 + 0], i31 = s_img[(pi + 3) * 3 + 1], i32 = s_img[(pi + 3) * 3 + 2];
    size_t base = (size_t)(py0 + r4) * WW + (size_t)(px0 + cq * 4);
    #pragma unroll 4
    for (int rnd = 0; rnd < DIMV / 16; ++rnd) {
        int dd = rnd * 16 + wv * 4 + sub;
        float4 wb = s_wub[dd];
        float4 v;
        v.x = fmaf(wb.x, i00, fmaf(wb.y, i01, fmaf(wb.z, i02, wb.w)));
        v.y = fmaf(wb.x, i10, fmaf(wb.y, i11, fmaf(wb.z, i12, wb.w)));
        v.z = fmaf(wb.x, i20, fmaf(wb.y, i21, fmaf(wb.z, i22, wb.w)));
        v.w = fmaf(wb.x, i30, fmaf(wb.y, i31, fmaf(wb.z, i32, wb.w)));
        *(float4*)(out + (size_t)dd * PIX + base) = v;
    }
}

extern "C" void kernel_launch(void* const* d_in, const int* in_sizes, int n_in,
                              void* d_out, int out_size, void* d_ws, size_t ws_size,
                              hipStream_t stream)
{
    // setup_inputs order: x(unused), xyz, scaling, rotation, features, opacity, w_up, b_up
    const float* xyz      = (const float*)d_in[1];
    const float* scaling  = (const float*)d_in[2];
    const float* rotation = (const float*)d_in[3];
    const float* features = (const float*)d_in[4];
    const float* opacity  = (const float*)d_in[5];
    const float* w_up     = (const float*)d_in[6];
    const float* b_up     = (const float*)d_in[7];
    float* out = (float*)d_out;

    float4* q0 = (float4*)d_ws;
    float4* q1 = q0 + NG;
    float2* q2 = (float2*)(q1 + NG);

    prep_kernel<<<NG / 256, 256, 0, stream>>>(xyz, scaling, rotation, features,
                                              opacity, q0, q1, q2);
    raster_kernel<<<256, 256, 0, stream>>>(q0, q1, q2, w_up, b_up, out);
}

// Round 2
// 114.306 us; speedup vs baseline: 1.1336x; 1.1336x over previous
//
#include <hip/hip_runtime.h>
#include <math.h>

#define HH 128
#define WW 128
#define NG 2048
#define DIMV 768
#define PIX (HH * WW)
#define A_MIN (1.0f / 255.0f)
#define TW 16
#define TH 4
#define TWO_PI 6.28318530717958647692f

// ---------------------------------------------------------------------------
// K1: one 16x4 pixel tile per block (256 blocks, 256 threads = 4 waves).
//  Phase A: all blocks redundantly compute per-gaussian conic/color/radius
//           into LDS (8 gaussians/thread, fast transcendentals).
//  Phase B: cull 2048 gaussians vs tile rect (LDS-atomic compaction).
//           Bound is exact-conservative: alpha>=1/255 requires
//           sigma <= ln(255*op); sigma >= |d|^2/(2*lmax) and lmax < cxx+cyy.
//  Phase C: 4-way wave split over survivors; params via wave-uniform
//           ds_read_b128 broadcast. 1 pixel/lane.
//  Phase D: cross-wave reduce, clip, store img planes (r,g,b) to ws.
// ---------------------------------------------------------------------------
__global__ __launch_bounds__(256) void raster_kernel(
    const float* __restrict__ xyz, const float* __restrict__ scaling,
    const float* __restrict__ rotation, const float* __restrict__ features,
    const float* __restrict__ opacity, float* __restrict__ img)
{
    __shared__ float4 sP0[NG];          // (A/2, B, C/2, op)
    __shared__ float4 sP1[NG];          // (gx, gy, f0, f1)
    __shared__ float2 sP2[NG];          // (f2, r2)
    __shared__ int s_cnt;
    __shared__ int s_list[NG];
    __shared__ float s_red[4 * 64 * 3];

    int tid = threadIdx.x;
    int bx = blockIdx.x & 7, by = blockIdx.x >> 3;
    int px0 = bx * TW, py0 = by * TH;

    if (tid == 0) s_cnt = 0;

    // ---- Phase A: per-gaussian params into LDS
    for (int g = tid; g < NG; g += 256) {
        float2 xz = ((const float2*)xyz)[g];
        float e2x = __expf(2.0f * xz.x);
        float e2y = 2.0f * __expf(2.0f * xz.y);  // premul trick below
        float gx = (e2x / (e2x + 1.0f)) * (float)WW;          // 0.5*(tanh+1)*W
        float gy = (e2y / (e2y + 2.0f)) * (float)HH;
        float2 sc = ((const float2*)scaling)[g];
        float s0 = fabsf(sc.x + 0.5f);
        float s1 = fabsf(sc.y + 0.5f);
        float th = TWO_PI / (1.0f + __expf(-rotation[g]));
        float sn = __sinf(th), cs = __cosf(th);
        float a = cs * s0, b = -sn * s1, d = sn * s0, e = cs * s1;
        float cxx = a * a + b * b;
        float cxy = a * d + b * e;
        float cyy = d * d + e * e;
        float inv = 1.0f / (cxx * cyy - cxy * cxy);   // det >= (s0*s1)^2 >= 1/16
        float op = opacity[g];
        float L = __logf(255.0f * op);
        float r2 = (L > 0.0f) ? 2.0f * L * (cxx + cyy) * 1.0002f + 1e-3f : -1.0f;
        sP0[g] = make_float4(0.5f * cyy * inv, -cxy * inv, 0.5f * cxx * inv, op);
        sP1[g] = make_float4(gx, gy, features[3 * g + 0], features[3 * g + 1]);
        sP2[g] = make_float2(features[3 * g + 2], r2);
    }
    __syncthreads();

    // ---- Phase B: cull vs rect of pixel centers
    {
        float x0 = px0 + 0.5f, x1 = px0 + TW - 0.5f;
        float y0 = py0 + 0.5f, y1 = py0 + TH - 0.5f;
        for (int g = tid; g < NG; g += 256) {
            float4 c1 = sP1[g];
            float2 c2 = sP2[g];
            float ddx = fmaxf(fmaxf(x0 - c1.x, c1.x - x1), 0.0f);
            float ddy = fmaxf(fmaxf(y0 - c1.y, c1.y - y1), 0.0f);
            if (ddx * ddx + ddy * ddy <= c2.y) {
                int pos = atomicAdd(&s_cnt, 1);
                s_list[pos] = g;
            }
        }
    }
    __syncthreads();
    int cnt = s_cnt;

    int lane = tid & 63, wv = tid >> 6;
    float pxf = px0 + (lane & 15) + 0.5f;
    float pyf = py0 + (lane >> 4) + 0.5f;

    // ---- Phase C: alpha-weighted color accumulation
    float ar = 0.0f, ag = 0.0f, ab = 0.0f;
    for (int k = wv; k < cnt; k += 4) {
        int g = __builtin_amdgcn_readfirstlane(s_list[k]);
        float4 a0 = sP0[g];
        float4 a1 = sP1[g];
        float2 a2 = sP2[g];
        float dx = a1.x - pxf, dy = a1.y - pyf;
        float sig = fmaf(a0.y * dx, dy, fmaf(a0.x * dx, dx, a0.z * dy * dy));
        float al = fminf(0.999f, a0.w * __expf(-sig));
        al = (sig < 0.0f || al < A_MIN) ? 0.0f : al;
        ar = fmaf(al, a1.z, ar);
        ag = fmaf(al, a1.w, ag);
        ab = fmaf(al, a2.x, ab);
    }
    s_red[(wv * 64 + lane) * 3 + 0] = ar;
    s_red[(wv * 64 + lane) * 3 + 1] = ag;
    s_red[(wv * 64 + lane) * 3 + 2] = ab;
    __syncthreads();

    // ---- Phase D: reduce across waves, clip, store img planes
    if (tid < 64) {
        float sr = 0.0f, sg = 0.0f, sb = 0.0f;
        #pragma unroll
        for (int w = 0; w < 4; ++w) {
            sr += s_red[(w * 64 + tid) * 3 + 0];
            sg += s_red[(w * 64 + tid) * 3 + 1];
            sb += s_red[(w * 64 + tid) * 3 + 2];
        }
        int p = (py0 + (tid >> 4)) * WW + px0 + (tid & 15);
        img[p]           = fminf(1.0f, fmaxf(0.0f, sr));
        img[PIX + p]     = fminf(1.0f, fmaxf(0.0f, sg));
        img[2 * PIX + p] = fminf(1.0f, fmaxf(0.0f, sb));
    }
}

// ---------------------------------------------------------------------------
// K2: projection to 768 channels. 3072 blocks (12/CU): blockIdx = grp*16+seg,
// grp -> 4 consecutive channels, seg -> 1024-pixel span. Pure write-bound:
// 3x float4 L2-resident img reads, 16 FMA, 4x float4 coalesced stores.
// ---------------------------------------------------------------------------
__global__ __launch_bounds__(256) void project_kernel(
    const float* __restrict__ img, const float* __restrict__ w_up,
    const float* __restrict__ b_up, float* __restrict__ out)
{
    int grp = blockIdx.x >> 4;
    int seg = blockIdx.x & 15;
    int p = seg * 1024 + threadIdx.x * 4;
    float4 r = *(const float4*)(img + p);
    float4 g = *(const float4*)(img + PIX + p);
    float4 b = *(const float4*)(img + 2 * PIX + p);
    int d0 = grp * 4;
    #pragma unroll
    for (int i = 0; i < 4; ++i) {
        int d = d0 + i;
        float w0 = w_up[3 * d + 0], w1 = w_up[3 * d + 1], w2 = w_up[3 * d + 2];
        float bb = b_up[d];
        float4 v;
        v.x = fmaf(w0, r.x, fmaf(w1, g.x, fmaf(w2, b.x, bb)));
        v.y = fmaf(w0, r.y, fmaf(w1, g.y, fmaf(w2, b.y, bb)));
        v.z = fmaf(w0, r.z, fmaf(w1, g.z, fmaf(w2, b.z, bb)));
        v.w = fmaf(w0, r.w, fmaf(w1, g.w, fmaf(w2, b.w, bb)));
        *(float4*)(out + (size_t)d * PIX + p) = v;
    }
}

extern "C" void kernel_launch(void* const* d_in, const int* in_sizes, int n_in,
                              void* d_out, int out_size, void* d_ws, size_t ws_size,
                              hipStream_t stream)
{
    // setup_inputs order: x(unused), xyz, scaling, rotation, features, opacity, w_up, b_up
    const float* xyz      = (const float*)d_in[1];
    const float* scaling  = (const float*)d_in[2];
    const float* rotation = (const float*)d_in[3];
    const float* features = (const float*)d_in[4];
    const float* opacity  = (const float*)d_in[5];
    const float* w_up     = (const float*)d_in[6];
    const float* b_up     = (const float*)d_in[7];
    float* out = (float*)d_out;
    float* img = (float*)d_ws;   // 3 planes of PIX floats (192 KB)

    raster_kernel<<<256, 256, 0, stream>>>(xyz, scaling, rotation, features,
                                           opacity, img);
    project_kernel<<<(DIMV / 4) * 16, 256, 0, stream>>>(img, w_up, b_up, out);
}